// Round 2
// baseline (80.215 us; speedup 1.0000x reference)
//
#include <hip/hip_runtime.h>

#define FL 9
#define CIN 16
#define COUT 16
#define T_IN 2048
#define T_OUT 2040
#define NB 2
#define TTILE 16
#define XW (TTILE + FL - 1)  // 24

__global__ __launch_bounds__(1024) void qconv_kernel(
    const float* __restrict__ x, const float* __restrict__ pa,
    const float* __restrict__ pb, const float* __restrict__ pc,
    float* __restrict__ out)
{
    __shared__ float4 xs[CIN][XW];          // 6144 B
    __shared__ float4 pabc[COUT * CIN * FL];// 36864 B (a,b,c,pad)
    __shared__ float4 red[3][COUT * TTILE]; // 12288 B

    const int tid   = threadIdx.x;
    const int batch = blockIdx.x >> 7;      // 128 tiles per batch
    const int tile  = blockIdx.x & 127;
    const int t0    = tile * TTILE;

    // stage params interleaved: one ds_read_b128 per term later
    for (int i = tid; i < COUT * CIN * FL; i += 1024) {
        pabc[i] = make_float4(pa[i], pb[i], pc[i], 0.0f);
    }
    // stage x tile (clamped at the right edge; clamped lanes only feed
    // outputs t >= T_OUT, which are guarded at the store)
    {
        const float4* xg = (const float4*)x;
        int i = tid;
        if (i < CIN * XW) {
            int cin = i / XW;
            int ii  = i - cin * XW;
            int t   = t0 + ii;
            if (t > T_IN - 1) t = T_IN - 1;
            xs[cin][ii] = xg[(batch * CIN + cin) * T_IN + t];
        }
    }
    __syncthreads();

    const int tl = tid & 15;          // t within tile
    const int co = (tid >> 4) & 15;   // cout
    const int cg = tid >> 8;          // cin group (0..3)

    float accw = 0.f, accx = 0.f, accy = 0.f, accz = 0.f;

    #pragma unroll
    for (int ci = 0; ci < 4; ++ci) {
        const int cin = cg * 4 + ci;
        const float4 qp = xs[cin][tl + 4];   // center tap (j = FL/2)
        const float px = qp.y, py = qp.z, pz = qp.w;
        const float h  = px * px + py * py + pz * pz;  // |vec(qp)|^2, j-invariant

        #pragma unroll
        for (int j = 0; j < FL; ++j) {
            const float4 qj = xs[cin][tl + j];
            const float4 p  = pabc[(co * CIN + cin) * FL + j];
            const float av = p.x, bv = p.y, cv = p.z;

            // quaternion components: (w,x,y,z) = (.x,.y,.z,.w) of float4
            const float aw = qj.x, ax = qj.y, ay = qj.z, az = qj.w;
            const float pw = qp.x + cv;           // only scalar part gets +c

            const float nsq = __builtin_fmaf(pw, pw, h);
            float rn = __builtin_amdgcn_rcpf(nsq);
            rn = rn * (2.0f - nsq * rn);          // 1 Newton step -> ~0.5 ulp

            // inner = hmul(q, conj(qpc))
            const float iw =  aw*pw + ax*px + ay*py + az*pz;
            const float ix = -aw*px + ax*pw - ay*pz + az*py;
            const float iy = -aw*py + ax*pz + ay*pw - az*px;
            const float iz = -aw*pz - ax*py + ay*px + az*pw;

            // t2 = hmul(qpc, inner); scalar part exactly aw*nsq
            // (Re(P Q conj(P)) = Re(Q)|P|^2)
            const float tw = aw * nsq;
            const float tx = pw*ix + px*iw + py*iz - pz*iy;
            const float ty = pw*iy - px*iz + py*iw + pz*ix;
            const float tz = pw*iz + px*iy - py*ix + pz*iw;

            // res2 = hmul(q, t2) + b*t2   (division deferred via linearity)
            const float rw = aw*tw - ax*tx - ay*ty - az*tz + bv*tw;
            const float rx = aw*tx + ax*tw + ay*tz - az*ty + bv*tx;
            const float ry = aw*ty - ax*tz + ay*tw + az*tx + bv*ty;
            const float rz = aw*tz + ax*ty - ay*tx + az*tw + bv*tz;

            const float s = av * rn;              // fold a and 1/nsq together
            accw = __builtin_fmaf(rw, s, accw);
            accx = __builtin_fmaf(rx, s, accx);
            accy = __builtin_fmaf(ry, s, accy);
            accz = __builtin_fmaf(rz, s, accz);
        }
    }

    // reduce the 4 cin-group partials through LDS
    if (cg != 0) {
        red[cg - 1][co * TTILE + tl] = make_float4(accw, accx, accy, accz);
    }
    __syncthreads();
    if (cg == 0) {
        const int t = t0 + tl;
        if (t < T_OUT) {
            const float4 r1 = red[0][tid];
            const float4 r2 = red[1][tid];
            const float4 r3 = red[2][tid];
            float4 o;
            o.x = accw + r1.x + r2.x + r3.x;
            o.y = accx + r1.y + r2.y + r3.y;
            o.z = accy + r1.z + r2.z + r3.z;
            o.w = accz + r1.w + r2.w + r3.w;
            ((float4*)out)[(batch * COUT + co) * T_OUT + t] = o;
        }
    }
}

extern "C" void kernel_launch(void* const* d_in, const int* in_sizes, int n_in,
                              void* d_out, int out_size, void* d_ws, size_t ws_size,
                              hipStream_t stream) {
    const float* x  = (const float*)d_in[0];
    const float* pa = (const float*)d_in[1];
    const float* pb = (const float*)d_in[2];
    const float* pc = (const float*)d_in[3];
    float* out = (float*)d_out;

    dim3 grid(NB * ((T_OUT + TTILE - 1) / TTILE));  // 2 * 128 = 256 blocks
    dim3 block(1024);
    qconv_kernel<<<grid, block, 0, stream>>>(x, pa, pb, pc, out);
}

// Round 3
// 76.049 us; speedup vs baseline: 1.0548x; 1.0548x over previous
//
#include <hip/hip_runtime.h>

#define FL 9
#define CIN 16
#define COUT 16
#define T_IN 2048
#define T_OUT 2040
#define TTILE 64
#define XW (TTILE + FL - 1)  // 72

// grid = 512 blocks: bid = b(1) | tile(5) | cinq(2) | cohalf(1)
// block = 256 threads = 64 t-local x 4 cin-local; wave <-> one cin (uniform)
// Each thread: one (t, cin), 8 couts, all 9 taps.
// Sandwich identity: res = (Q + b)*P*Q*conj(P) * (a/|P|^2), P = qp + c.
// P Q conj(P) = A2*pw^2 + A1*pw + A0 with A's independent of co/c:
//   A2 = Q, A1 = (0, 2 v x u), A0 = (qw h, 2(v.u)v - h u),  v=vec(qp), h=|v|^2
// (Q)*that = B2*pw^2 + B1*pw + B0, so res = (B + bv*A)(pw^2, pw, 1).
__global__ __launch_bounds__(256) void qconv_main(
    const float* __restrict__ x, const float* __restrict__ pa,
    const float* __restrict__ pb, const float* __restrict__ pc,
    float4* __restrict__ part)
{
    __shared__ float4 xs[4][XW];          // 4.5 KB
    __shared__ float4 red[3][8][TTILE];   // 24 KB, [cl-1][co][tl]: stride-16B writes

    const int bid    = blockIdx.x;
    const int cohalf = bid & 1;
    const int cinq   = (bid >> 1) & 3;
    const int tile   = (bid >> 3) & 31;
    const int b      = bid >> 8;
    const int t0     = tile * TTILE;

    const int tid = threadIdx.x;
    const int tl  = tid & 63;
    const int cl  = tid >> 6;            // wave index == cin-local
    const int cin = cinq * 4 + cl;

    // stage x window for this block's 4 cins (each wave stages its own cin)
    {
        const float4* xg = (const float4*)x + (b * CIN + cin) * T_IN;
        for (int i = tl; i < XW; i += 64) {
            int t = t0 + i;
            if (t > T_IN - 1) t = T_IN - 1;   // clamped lanes feed only guarded-out t
            xs[cl][i] = xg[t];
        }
    }
    __syncthreads();

    const float4 qp  = xs[cl][tl + 4];    // center tap j = FL/2
    const float  qpw = qp.x;
    const float  vx = qp.y, vy = qp.z, vz = qp.w;
    const float  h  = vx * vx + vy * vy + vz * vz;

    const int cin_s = __builtin_amdgcn_readfirstlane(cin);  // force scalar param addr
    const int cob   = cohalf * 8;

    float4 acc[8];
    #pragma unroll
    for (int co = 0; co < 8; ++co) acc[co] = make_float4(0.f, 0.f, 0.f, 0.f);

    #pragma unroll
    for (int j = 0; j < FL; ++j) {
        const float4 Q = xs[cl][tl + j];
        const float qw = Q.x, ux = Q.y, uy = Q.z, uz = Q.w;

        // shared-across-co coefficient quaternions
        const float cx = vy * uz - vz * uy;      // v x u
        const float cy = vz * ux - vx * uz;
        const float cz = vx * uy - vy * ux;
        const float d  = vx * ux + vy * uy + vz * uz;
        const float uu = ux * ux + uy * uy + uz * uz;

        const float a1x = cx + cx, a1y = cy + cy, a1z = cz + cz;  // A1 vec
        const float d2  = d + d;
        const float a0w = qw * h;
        const float a0x = d2 * vx - h * ux;
        const float a0y = d2 * vy - h * uy;
        const float a0z = d2 * vz - h * uz;

        const float b2w = qw * qw - uu;          // B2 = Q^2
        const float q2  = qw + qw;
        const float b2x = q2 * ux, b2y = q2 * uy, b2z = q2 * uz;

        // B1 = hmul(Q, (0, A1)) = (-u.A1, qw A1 + u x A1)
        const float b1w = -(ux * a1x + uy * a1y + uz * a1z);
        const float e1x = uy * a1z - uz * a1y;
        const float e1y = uz * a1x - ux * a1z;
        const float e1z = ux * a1y - uy * a1x;
        const float b1x = qw * a1x + e1x;
        const float b1y = qw * a1y + e1y;
        const float b1z = qw * a1z + e1z;

        // B0 = hmul(Q, A0) = (qw a0w - u.n, qw n + a0w u + u x n)
        const float b0w = qw * a0w - (ux * a0x + uy * a0y + uz * a0z);
        const float e0x = uy * a0z - uz * a0y;
        const float e0y = uz * a0x - ux * a0z;
        const float e0z = ux * a0y - uy * a0x;
        const float b0x = qw * a0x + a0w * ux + e0x;
        const float b0y = qw * a0y + a0w * uy + e0y;
        const float b0z = qw * a0z + a0w * uz + e0z;

        #pragma unroll
        for (int co = 0; co < 8; ++co) {
            const int pidx = ((cob + co) * CIN + cin_s) * FL + j;  // scalar address
            const float av = pa[pidx], bv = pb[pidx], cv = pc[pidx];

            const float pw  = qpw + cv;
            const float p2  = pw * pw;
            const float nsq = p2 + h;
            float rn = __builtin_amdgcn_rcpf(nsq);
            rn = rn * (2.0f - nsq * rn);          // 1 Newton step
            const float s = av * rn;

            const float f2w = __builtin_fmaf(bv, qw, b2w);
            const float f2x = __builtin_fmaf(bv, ux, b2x);
            const float f2y = __builtin_fmaf(bv, uy, b2y);
            const float f2z = __builtin_fmaf(bv, uz, b2z);
            const float f1x = __builtin_fmaf(bv, a1x, b1x);
            const float f1y = __builtin_fmaf(bv, a1y, b1y);
            const float f1z = __builtin_fmaf(bv, a1z, b1z);
            const float f0w = __builtin_fmaf(bv, a0w, b0w);
            const float f0x = __builtin_fmaf(bv, a0x, b0x);
            const float f0y = __builtin_fmaf(bv, a0y, b0y);
            const float f0z = __builtin_fmaf(bv, a0z, b0z);

            // A1w == 0, so F1w == b1w
            const float rw = __builtin_fmaf(f2w, p2, __builtin_fmaf(b1w, pw, f0w));
            const float rx = __builtin_fmaf(f2x, p2, __builtin_fmaf(f1x, pw, f0x));
            const float ry = __builtin_fmaf(f2y, p2, __builtin_fmaf(f1y, pw, f0y));
            const float rz = __builtin_fmaf(f2z, p2, __builtin_fmaf(f1z, pw, f0z));

            acc[co].x = __builtin_fmaf(rw, s, acc[co].x);
            acc[co].y = __builtin_fmaf(rx, s, acc[co].y);
            acc[co].z = __builtin_fmaf(ry, s, acc[co].z);
            acc[co].w = __builtin_fmaf(rz, s, acc[co].w);
        }
    }

    // cross-cin (4-way) reduce within block via LDS
    if (cl != 0) {
        #pragma unroll
        for (int co = 0; co < 8; ++co) red[cl - 1][co][tl] = acc[co];
    }
    __syncthreads();
    if (cl == 0) {
        const int t = t0 + tl;
        if (t < T_OUT) {
            #pragma unroll
            for (int co = 0; co < 8; ++co) {
                const float4 r0 = red[0][co][tl];
                const float4 r1 = red[1][co][tl];
                const float4 r2 = red[2][co][tl];
                float4 o;
                o.x = acc[co].x + r0.x + r1.x + r2.x;
                o.y = acc[co].y + r0.y + r1.y + r2.y;
                o.z = acc[co].z + r0.z + r1.z + r2.z;
                o.w = acc[co].w + r0.w + r1.w + r2.w;
                // part[(cinq*32 + b*16 + co_global)][t], t-stride 2048
                part[(cinq * 32 + b * 16 + cob + co) * 2048 + t] = o;
            }
        }
    }
}

// sum the 4 cin-quarter partials -> d_out
__global__ __launch_bounds__(256) void qconv_reduce(
    const float4* __restrict__ part, float4* __restrict__ out)
{
    const int N = 2 * COUT * T_OUT;  // 65280 float4s
    for (int i = blockIdx.x * 256 + threadIdx.x; i < N; i += gridDim.x * 256) {
        const int t  = i % T_OUT;
        const int bc = i / T_OUT;    // b*16 + co
        const float4 p0 = part[(0 * 32 + bc) * 2048 + t];
        const float4 p1 = part[(1 * 32 + bc) * 2048 + t];
        const float4 p2 = part[(2 * 32 + bc) * 2048 + t];
        const float4 p3 = part[(3 * 32 + bc) * 2048 + t];
        float4 o;
        o.x = (p0.x + p1.x) + (p2.x + p3.x);
        o.y = (p0.y + p1.y) + (p2.y + p3.y);
        o.z = (p0.z + p1.z) + (p2.z + p3.z);
        o.w = (p0.w + p1.w) + (p2.w + p3.w);
        out[i] = o;
    }
}

extern "C" void kernel_launch(void* const* d_in, const int* in_sizes, int n_in,
                              void* d_out, int out_size, void* d_ws, size_t ws_size,
                              hipStream_t stream) {
    const float* x  = (const float*)d_in[0];
    const float* pa = (const float*)d_in[1];
    const float* pb = (const float*)d_in[2];
    const float* pc = (const float*)d_in[3];
    float4* part = (float4*)d_ws;     // 4 quarters x 32 (b,co) x 2048 float4 = 16 MB
    float4* out  = (float4*)d_out;

    qconv_main<<<dim3(512), dim3(256), 0, stream>>>(x, pa, pb, pc, part);
    qconv_reduce<<<dim3(256), dim3(256), 0, stream>>>(part, out);
}